// Round 3
// baseline (74.414 us; speedup 1.0000x reference)
//
#include <hip/hip_runtime.h>
#include <hip/hip_bf16.h>

// Sizes fixed by the problem
#define Bb 4
#define Nn 256
#define Dd 128
#define Hh 8
#define Kk 16
#define HK 128          // H*K
#define BN 1024         // B*N

// Kernel 1: Q = h@Wq, K = h@Wk * K^-0.5, V = h@Wv  (f32 into workspace)
__global__ __launch_bounds__(128) void qkv_kernel(
    const float* __restrict__ h,
    const float* __restrict__ Wq,
    const float* __restrict__ Wk,
    const float* __restrict__ Wv,
    float* __restrict__ Qw, float* __restrict__ Kw, float* __restrict__ Vw)
{
    __shared__ float hrows[8][Dd];
    const int rb = blockIdx.x;          // rows rb*8 .. rb*8+7
    const int t  = threadIdx.x;         // output column 0..127
    #pragma unroll
    for (int r = 0; r < 8; ++r)
        hrows[r][t] = h[(size_t)(rb * 8 + r) * Dd + t];
    __syncthreads();

    float aq[8], ak[8], av[8];
    #pragma unroll
    for (int r = 0; r < 8; ++r) { aq[r] = 0.f; ak[r] = 0.f; av[r] = 0.f; }

    for (int d = 0; d < Dd; ++d) {
        const float wq = Wq[d * HK + t];
        const float wk = Wk[d * HK + t];
        const float wv = Wv[d * HK + t];
        #pragma unroll
        for (int r = 0; r < 8; ++r) {
            const float hv = hrows[r][d];
            aq[r] = fmaf(hv, wq, aq[r]);
            ak[r] = fmaf(hv, wk, ak[r]);
            av[r] = fmaf(hv, wv, av[r]);
        }
    }
    #pragma unroll
    for (int r = 0; r < 8; ++r) {
        const size_t o = (size_t)(rb * 8 + r) * HK + t;
        Qw[o] = aq[r];
        Kw[o] = ak[r] * 0.25f;              // K^-0.5 = 1/sqrt(16)
        Vw[o] = av[r];
    }
}

// Kernel 2: qk[b,i,j,h] = sum_k Q[b,i,h,k]*Kscaled[b,j,h,k]
// One block per (b,i); thread handles (j,h) with a CONTIGUOUS 64B K read.
__global__ __launch_bounds__(256) void qk_kernel(
    const float* __restrict__ Qw,
    const float* __restrict__ Kw,
    float* __restrict__ qkg)
{
    __shared__ float qrow[HK];
    const int t  = threadIdx.x;
    const int bi = blockIdx.x;
    const int b  = bi >> 8;

    if (t < HK) qrow[t] = Qw[(size_t)bi * HK + t];
    __syncthreads();

    #pragma unroll
    for (int p = 0; p < 8; ++p) {
        const int idx = p * 256 + t;        // 0..2047
        const int j   = idx >> 3;
        const int hh  = idx & 7;
        const float4* kp = (const float4*)(Kw + (size_t)(b * Nn + j) * HK + hh * Kk);
        const float4 k0 = kp[0], k1 = kp[1], k2 = kp[2], k3 = kp[3];
        const float* qp = qrow + hh * Kk;
        float acc = 0.f;
        acc = fmaf(qp[0],  k0.x, acc); acc = fmaf(qp[1],  k0.y, acc);
        acc = fmaf(qp[2],  k0.z, acc); acc = fmaf(qp[3],  k0.w, acc);
        acc = fmaf(qp[4],  k1.x, acc); acc = fmaf(qp[5],  k1.y, acc);
        acc = fmaf(qp[6],  k1.z, acc); acc = fmaf(qp[7],  k1.w, acc);
        acc = fmaf(qp[8],  k2.x, acc); acc = fmaf(qp[9],  k2.y, acc);
        acc = fmaf(qp[10], k2.z, acc); acc = fmaf(qp[11], k2.w, acc);
        acc = fmaf(qp[12], k3.x, acc); acc = fmaf(qp[13], k3.y, acc);
        acc = fmaf(qp[14], k3.z, acc); acc = fmaf(qp[15], k3.w, acc);
        qkg[(size_t)bi * 2048 + idx] = acc;   // coalesced
    }
}

// Kernel 3: one block of 512 per (b,i). Memory-bound float4 sweep over
// e_att/e_val with online accumulation; qk row staged in LDS coalesced.
__global__ __launch_bounds__(512) void attn_kernel(
    const float* __restrict__ e_att,
    const float* __restrict__ e_val,
    const float* __restrict__ mask,
    const float* __restrict__ qkg,
    const float* __restrict__ Vw,
    float* __restrict__ out)
{
    __shared__ float qk_s[2048];            // qk[j*8+h], 8 KB
    __shared__ float mrow[Nn];              // mask[b,:]
    __shared__ float red[3 * 16 * HK];      // 24 KB reduce buffer

    const int t  = threadIdx.x;             // 0..511
    const int bi = blockIdx.x;              // b*N + i
    const int b  = bi >> 8;

    ((float4*)qk_s)[t] = ((const float4*)(qkg + (size_t)bi * 2048))[t];
    if (t < Nn) mrow[t] = mask[b * Nn + t];
    __syncthreads();

    const float maski = mrow[bi & 255];

    const int q32  = t & 31;                // 32 lanes cover one j row (128 f32)
    const int joff = t >> 5;                // 0..15
    const int hk4  = q32 * 4;               // owned hk block
    const int hh   = q32 >> 2;              // head of this hk block

    float acc_d[4] = {0,0,0,0}, acc_v[4] = {0,0,0,0}, acc_e[4] = {0,0,0,0};
    const size_t slice = (size_t)bi * (Nn * HK);

    #pragma unroll 4
    for (int jb = 0; jb < Nn; jb += 16) {
        const int j = jb + joff;
        const size_t eoff = slice + (size_t)j * HK + hk4;
        const float4 ea = *(const float4*)(e_att + eoff);
        const float4 ev = *(const float4*)(e_val + eoff);
        const float4 v4 = *(const float4*)(Vw + (size_t)(b * Nn + j) * HK + hk4);

        const float qk = qk_s[(j << 3) + hh];
        const float m  = maski * mrow[j];
        const float m2 = m * m;

        const float eaf[4] = {ea.x, ea.y, ea.z, ea.w};
        const float evf[4] = {ev.x, ev.y, ev.z, ev.w};
        const float vv[4]  = {v4.x, v4.y, v4.z, v4.w};

        #pragma unroll
        for (int l = 0; l < 4; ++l) {
            float x = qk + eaf[l];
            x = fminf(fmaxf(x, -5.f), 5.f);
            const float e = __expf(x);
            acc_d[l] = fmaf(e, m, acc_d[l]);   // denom uses scores*m
            const float s2 = e * m2;           // numerator uses scores*m^2
            acc_v[l] = fmaf(s2, vv[l], acc_v[l]);
            acc_e[l] = fmaf(s2, evf[l], acc_e[l]);
        }
    }
    __syncthreads();

    // reduce 16 j-partials per hk
    #pragma unroll
    for (int l = 0; l < 4; ++l) {
        red[0 * 2048 + joff * HK + hk4 + l] = acc_d[l];
        red[1 * 2048 + joff * HK + hk4 + l] = acc_v[l];
        red[2 * 2048 + joff * HK + hk4 + l] = acc_e[l];
    }
    __syncthreads();

    if (t < HK) {
        float D = 0.f, OV = 0.f, OE = 0.f;
        #pragma unroll
        for (int p = 0; p < 16; ++p) {
            D  += red[0 * 2048 + p * HK + t];
            OV += red[1 * 2048 + p * HK + t];
            OE += red[2 * 2048 + p * HK + t];
        }
        out[(size_t)bi * HK + t] = (OV + OE) / fmaxf(D, 1e-6f);
    }
}

extern "C" void kernel_launch(void* const* d_in, const int* in_sizes, int n_in,
                              void* d_out, int out_size, void* d_ws, size_t ws_size,
                              hipStream_t stream) {
    const float* h     = (const float*)d_in[0];
    const float* e_att = (const float*)d_in[1];
    const float* e_val = (const float*)d_in[2];
    const float* mask  = (const float*)d_in[3];
    const float* Wq    = (const float*)d_in[4];
    const float* Wk    = (const float*)d_in[5];
    const float* Wv    = (const float*)d_in[6];
    float* out = (float*)d_out;

    float* Qw  = (float*)d_ws;              // 131072 f32
    float* Kw  = Qw + (size_t)BN * HK;      // 131072 f32
    float* Vw  = Kw + (size_t)BN * HK;      // 131072 f32
    float* qkg = Vw + (size_t)BN * HK;      // 2097152 f32 (8 MiB) -> total ~9.5 MiB

    qkv_kernel<<<128, 128, 0, stream>>>(h, Wq, Wk, Wv, Qw, Kw, Vw);
    qk_kernel<<<BN, 256, 0, stream>>>(Qw, Kw, qkg);
    attn_kernel<<<BN, 512, 0, stream>>>(e_att, e_val, mask, qkg, Vw, out);
}

// Round 4
// 73.623 us; speedup vs baseline: 1.0107x; 1.0107x over previous
//
#include <hip/hip_runtime.h>
#include <hip/hip_bf16.h>

// Sizes fixed by the problem
#define Bb 4
#define Nn 256
#define Dd 128
#define Hh 8
#define Kk 16
#define HK 128          // H*K
#define BN 1024         // B*N

// Kernel 1: Q = h@Wq, K = h@Wk * K^-0.5, V = h@Wv  (f32 into workspace)
__global__ __launch_bounds__(128) void qkv_kernel(
    const float* __restrict__ h,
    const float* __restrict__ Wq,
    const float* __restrict__ Wk,
    const float* __restrict__ Wv,
    float* __restrict__ Qw, float* __restrict__ Kw, float* __restrict__ Vw)
{
    __shared__ float hrows[8][Dd];
    const int rb = blockIdx.x;          // rows rb*8 .. rb*8+7
    const int t  = threadIdx.x;         // output column 0..127
    #pragma unroll
    for (int r = 0; r < 8; ++r)
        hrows[r][t] = h[(size_t)(rb * 8 + r) * Dd + t];
    __syncthreads();

    float aq[8], ak[8], av[8];
    #pragma unroll
    for (int r = 0; r < 8; ++r) { aq[r] = 0.f; ak[r] = 0.f; av[r] = 0.f; }

    for (int d = 0; d < Dd; ++d) {
        const float wq = Wq[d * HK + t];
        const float wk = Wk[d * HK + t];
        const float wv = Wv[d * HK + t];
        #pragma unroll
        for (int r = 0; r < 8; ++r) {
            const float hv = hrows[r][d];
            aq[r] = fmaf(hv, wq, aq[r]);
            ak[r] = fmaf(hv, wk, ak[r]);
            av[r] = fmaf(hv, wv, av[r]);
        }
    }
    #pragma unroll
    for (int r = 0; r < 8; ++r) {
        const size_t o = (size_t)(rb * 8 + r) * HK + t;
        Qw[o] = aq[r];
        Kw[o] = ak[r] * 0.25f;              // K^-0.5 = 1/sqrt(16)
        Vw[o] = av[r];
    }
}

// Fused kernel: one block of 512 per (b,i).
//   Phase B: qk[j][h] with per-thread CONTIGUOUS 256B K reads, padded LDS.
//   Phase C: software-pipelined float4 sweep over e_att/e_val.
#define QKP 9   // padded qk row stride (words) -> no LDS write conflicts

__global__ __launch_bounds__(512) void attn_kernel(
    const float* __restrict__ e_att,
    const float* __restrict__ e_val,
    const float* __restrict__ mask,
    const float* __restrict__ Qw,
    const float* __restrict__ Kw,
    const float* __restrict__ Vw,
    float* __restrict__ out)
{
    __shared__ float qrow[HK];              // Q[b,i,:,:]  0.5 KB
    __shared__ float mrow[Nn];              // mask[b,:]   1 KB
    __shared__ float qk_s[Nn * QKP];        // qk, padded  9 KB
    __shared__ float red[3 * 16 * HK];      // reduce buf  24 KB

    const int t  = threadIdx.x;             // 0..511
    const int bi = blockIdx.x;              // b*N + i
    const int b  = bi >> 8;

    if (t < HK) qrow[t] = Qw[(size_t)bi * HK + t];
    if (t < Nn) mrow[t] = mask[b * Nn + t];
    __syncthreads();

    const float maski = mrow[bi & 255];

    // ---- Phase B: thread t -> (j = t>>1, half = t&1), 4 heads each ----
    {
        const int j    = t >> 1;
        const int half = t & 1;             // heads half*4 .. half*4+3
        const float4* kp = (const float4*)(Kw + (size_t)(b * Nn + j) * HK + half * 64);
        const float*  qp = qrow + half * 64;
        #pragma unroll
        for (int hl = 0; hl < 4; ++hl) {
            const float4 k0 = kp[hl * 4 + 0], k1 = kp[hl * 4 + 1];
            const float4 k2 = kp[hl * 4 + 2], k3 = kp[hl * 4 + 3];
            const float* q = qp + hl * Kk;
            float acc = 0.f;
            acc = fmaf(q[0],  k0.x, acc); acc = fmaf(q[1],  k0.y, acc);
            acc = fmaf(q[2],  k0.z, acc); acc = fmaf(q[3],  k0.w, acc);
            acc = fmaf(q[4],  k1.x, acc); acc = fmaf(q[5],  k1.y, acc);
            acc = fmaf(q[6],  k1.z, acc); acc = fmaf(q[7],  k1.w, acc);
            acc = fmaf(q[8],  k2.x, acc); acc = fmaf(q[9],  k2.y, acc);
            acc = fmaf(q[10], k2.z, acc); acc = fmaf(q[11], k2.w, acc);
            acc = fmaf(q[12], k3.x, acc); acc = fmaf(q[13], k3.y, acc);
            acc = fmaf(q[14], k3.z, acc); acc = fmaf(q[15], k3.w, acc);
            qk_s[j * QKP + half * 4 + hl] = acc;
        }
    }
    __syncthreads();

    // ---- Phase C: pipelined sweep ----
    const int q32  = t & 31;                // 32 lanes cover one j row
    const int joff = t >> 5;                // 0..15
    const int hk4  = q32 * 4;
    const int hh   = q32 >> 2;

    float acc_d[4] = {0,0,0,0}, acc_v[4] = {0,0,0,0}, acc_e[4] = {0,0,0,0};
    const size_t slice = (size_t)bi * (Nn * HK);
    const float* vbase = Vw + (size_t)(b * Nn) * HK;

#define LOADSET(EA, EV, VV, JB) do {                                         \
        const int j_ = (JB) + joff;                                          \
        const size_t eo_ = slice + (size_t)j_ * HK + hk4;                    \
        EA = *(const float4*)(e_att + eo_);                                  \
        EV = *(const float4*)(e_val + eo_);                                  \
        VV = *(const float4*)(vbase + (size_t)j_ * HK + hk4);                \
    } while (0)

#define COMPUTE(EA, EV, VV, JB) do {                                         \
        const int j_ = (JB) + joff;                                          \
        const float qk_ = qk_s[j_ * QKP + hh];                               \
        const float m_  = maski * mrow[j_];                                  \
        const float m2_ = m_ * m_;                                           \
        const float eaf_[4] = {EA.x, EA.y, EA.z, EA.w};                      \
        const float evf_[4] = {EV.x, EV.y, EV.z, EV.w};                      \
        const float vvf_[4] = {VV.x, VV.y, VV.z, VV.w};                      \
        _Pragma("unroll")                                                    \
        for (int l = 0; l < 4; ++l) {                                        \
            float x_ = qk_ + eaf_[l];                                        \
            x_ = fminf(fmaxf(x_, -5.f), 5.f);                                \
            const float e_ = __expf(x_);                                     \
            acc_d[l] = fmaf(e_, m_, acc_d[l]);                               \
            const float s2_ = e_ * m2_;                                      \
            acc_v[l] = fmaf(s2_, vvf_[l], acc_v[l]);                         \
            acc_e[l] = fmaf(s2_, evf_[l], acc_e[l]);                         \
        }                                                                    \
    } while (0)

    float4 eaA, evA, vvA, eaB, evB, vvB;
    LOADSET(eaA, evA, vvA, 0);
    LOADSET(eaB, evB, vvB, 16);

    #pragma unroll
    for (int k = 0; k < 7; ++k) {
        const int jb = k * 32;
        COMPUTE(eaA, evA, vvA, jb);
        LOADSET(eaA, evA, vvA, jb + 32);
        COMPUTE(eaB, evB, vvB, jb + 16);
        LOADSET(eaB, evB, vvB, jb + 48);
    }
    COMPUTE(eaA, evA, vvA, 224);
    COMPUTE(eaB, evB, vvB, 240);

#undef LOADSET
#undef COMPUTE

    __syncthreads();

    // ---- reduce 16 j-partials per hk ----
    #pragma unroll
    for (int l = 0; l < 4; ++l) {
        red[0 * 2048 + joff * HK + hk4 + l] = acc_d[l];
        red[1 * 2048 + joff * HK + hk4 + l] = acc_v[l];
        red[2 * 2048 + joff * HK + hk4 + l] = acc_e[l];
    }
    __syncthreads();

    if (t < HK) {
        float D = 0.f, OV = 0.f, OE = 0.f;
        #pragma unroll
        for (int p = 0; p < 16; ++p) {
            D  += red[0 * 2048 + p * HK + t];
            OV += red[1 * 2048 + p * HK + t];
            OE += red[2 * 2048 + p * HK + t];
        }
        out[(size_t)bi * HK + t] = (OV + OE) / fmaxf(D, 1e-6f);
    }
}

extern "C" void kernel_launch(void* const* d_in, const int* in_sizes, int n_in,
                              void* d_out, int out_size, void* d_ws, size_t ws_size,
                              hipStream_t stream) {
    const float* h     = (const float*)d_in[0];
    const float* e_att = (const float*)d_in[1];
    const float* e_val = (const float*)d_in[2];
    const float* mask  = (const float*)d_in[3];
    const float* Wq    = (const float*)d_in[4];
    const float* Wk    = (const float*)d_in[5];
    const float* Wv    = (const float*)d_in[6];
    float* out = (float*)d_out;

    float* Qw  = (float*)d_ws;              // 131072 f32
    float* Kw  = Qw + (size_t)BN * HK;      // 131072 f32
    float* Vw  = Kw + (size_t)BN * HK;      // 131072 f32 (total 1.5 MiB)

    qkv_kernel<<<128, 128, 0, stream>>>(h, Wq, Wk, Wv, Qw, Kw, Vw);
    attn_kernel<<<BN, 512, 0, stream>>>(e_att, e_val, mask, Qw, Kw, Vw, out);
}

// Round 6
// 72.719 us; speedup vs baseline: 1.0233x; 1.0124x over previous
//
#include <hip/hip_runtime.h>
#include <hip/hip_bf16.h>

// Sizes fixed by the problem
#define Bb 4
#define Nn 256
#define Dd 128
#define Hh 8
#define Kk 16
#define HK 128          // H*K
#define BN 1024         // B*N

typedef float vf4 __attribute__((ext_vector_type(4)));   // native vec for NT builtins

__device__ __forceinline__ vf4 ntload4(const float* p) {
    return __builtin_nontemporal_load((const vf4*)p);
}
__device__ __forceinline__ vf4 ld4(const float* p) {
    return *(const vf4*)p;
}

// Kernel 1: Q = h@Wq, K = h@Wk * K^-0.5, V = h@Wv  (f32 into workspace)
// 512 blocks x 128 threads, 2 rows/block; d-loop unrolled x8 so 24 W-loads
// are in flight per chunk.
__global__ __launch_bounds__(128) void qkv_kernel(
    const float* __restrict__ h,
    const float* __restrict__ Wq,
    const float* __restrict__ Wk,
    const float* __restrict__ Wv,
    float* __restrict__ Qw, float* __restrict__ Kw, float* __restrict__ Vw)
{
    __shared__ float hrows[2][Dd];
    const int rb = blockIdx.x;          // rows rb*2, rb*2+1
    const int t  = threadIdx.x;         // output column 0..127
    hrows[0][t] = h[(size_t)(rb * 2 + 0) * Dd + t];
    hrows[1][t] = h[(size_t)(rb * 2 + 1) * Dd + t];
    __syncthreads();

    float aq0 = 0.f, aq1 = 0.f, ak0 = 0.f, ak1 = 0.f, av0 = 0.f, av1 = 0.f;
    for (int d0 = 0; d0 < Dd; d0 += 8) {
        float wq[8], wk[8], wv[8];
        #pragma unroll
        for (int u = 0; u < 8; ++u) {
            wq[u] = Wq[(d0 + u) * HK + t];
            wk[u] = Wk[(d0 + u) * HK + t];
            wv[u] = Wv[(d0 + u) * HK + t];
        }
        #pragma unroll
        for (int u = 0; u < 8; ++u) {
            const float h0 = hrows[0][d0 + u];
            const float h1 = hrows[1][d0 + u];
            aq0 = fmaf(h0, wq[u], aq0); aq1 = fmaf(h1, wq[u], aq1);
            ak0 = fmaf(h0, wk[u], ak0); ak1 = fmaf(h1, wk[u], ak1);
            av0 = fmaf(h0, wv[u], av0); av1 = fmaf(h1, wv[u], av1);
        }
    }
    const size_t o0 = (size_t)(rb * 2 + 0) * HK + t;
    const size_t o1 = (size_t)(rb * 2 + 1) * HK + t;
    Qw[o0] = aq0;          Qw[o1] = aq1;
    Kw[o0] = ak0 * 0.25f;  Kw[o1] = ak1 * 0.25f;   // K^-0.5 = 1/sqrt(16)
    Vw[o0] = av0;          Vw[o1] = av1;
}

// Fused kernel: one block of 512 per (b,i).
//   XCD-chunked swizzle: 128 consecutive work-items per XCD -> K/V L2-local.
//   Phase B: qk[j][h] with per-thread CONTIGUOUS 256B K reads, padded LDS.
//   Phase C: 2-deep pipelined float4 sweep; e-streams via NT loads (no L2 alloc).
#define QKP 9   // padded qk row stride (words) -> no LDS write conflicts

__global__ __launch_bounds__(512) void attn_kernel(
    const float* __restrict__ e_att,
    const float* __restrict__ e_val,
    const float* __restrict__ mask,
    const float* __restrict__ Qw,
    const float* __restrict__ Kw,
    const float* __restrict__ Vw,
    float* __restrict__ out)
{
    __shared__ float qrow[HK];              // Q[b,i,:,:]  0.5 KB
    __shared__ float mrow[Nn];              // mask[b,:]   1 KB
    __shared__ float qk_s[Nn * QKP];        // qk, padded  9 KB
    __shared__ float red[3 * 16 * HK];      // reduce buf  24 KB

    const int t  = threadIdx.x;             // 0..511
    // bijective XCD-chunk swizzle (1024 % 8 == 0): XCD x -> work [128x,128x+128)
    const int bi = ((blockIdx.x & 7) << 7) | (blockIdx.x >> 3);
    const int b  = bi >> 8;

    if (t < HK) qrow[t] = Qw[(size_t)bi * HK + t];
    if (t < Nn) mrow[t] = mask[b * Nn + t];
    __syncthreads();

    const float maski = mrow[bi & 255];

    // ---- Phase B: thread t -> (j = t>>1, half = t&1), 4 heads each ----
    {
        const int j    = t >> 1;
        const int half = t & 1;             // heads half*4 .. half*4+3
        const float*  kb = Kw + (size_t)(b * Nn + j) * HK + half * 64;
        const float*  qp = qrow + half * 64;
        #pragma unroll
        for (int hl = 0; hl < 4; ++hl) {
            const vf4 k0 = ld4(kb + hl * 16 + 0), k1 = ld4(kb + hl * 16 + 4);
            const vf4 k2 = ld4(kb + hl * 16 + 8), k3 = ld4(kb + hl * 16 + 12);
            const float* q = qp + hl * Kk;
            float acc = 0.f;
            acc = fmaf(q[0],  k0.x, acc); acc = fmaf(q[1],  k0.y, acc);
            acc = fmaf(q[2],  k0.z, acc); acc = fmaf(q[3],  k0.w, acc);
            acc = fmaf(q[4],  k1.x, acc); acc = fmaf(q[5],  k1.y, acc);
            acc = fmaf(q[6],  k1.z, acc); acc = fmaf(q[7],  k1.w, acc);
            acc = fmaf(q[8],  k2.x, acc); acc = fmaf(q[9],  k2.y, acc);
            acc = fmaf(q[10], k2.z, acc); acc = fmaf(q[11], k2.w, acc);
            acc = fmaf(q[12], k3.x, acc); acc = fmaf(q[13], k3.y, acc);
            acc = fmaf(q[14], k3.z, acc); acc = fmaf(q[15], k3.w, acc);
            qk_s[j * QKP + half * 4 + hl] = acc;
        }
    }
    __syncthreads();

    // ---- Phase C: pipelined sweep ----
    const int q32  = t & 31;                // 32 lanes cover one j row
    const int joff = t >> 5;                // 0..15
    const int hk4  = q32 * 4;
    const int hh   = q32 >> 2;

    float acc_d[4] = {0,0,0,0}, acc_v[4] = {0,0,0,0}, acc_e[4] = {0,0,0,0};
    const size_t slice = (size_t)bi * (Nn * HK);
    const float* vbase = Vw + (size_t)(b * Nn) * HK;

#define LOADSET(EA, EV, VV, JB) do {                                         \
        const int j_ = (JB) + joff;                                          \
        const size_t eo_ = slice + (size_t)j_ * HK + hk4;                    \
        EA = ntload4(e_att + eo_);                                           \
        EV = ntload4(e_val + eo_);                                           \
        VV = ld4(vbase + (size_t)j_ * HK + hk4);                             \
    } while (0)

#define COMPUTE(EA, EV, VV, JB) do {                                         \
        const int j_ = (JB) + joff;                                          \
        const float qk_ = qk_s[j_ * QKP + hh];                               \
        const float m_  = maski * mrow[j_];                                  \
        const float m2_ = m_ * m_;                                           \
        const float eaf_[4] = {EA.x, EA.y, EA.z, EA.w};                      \
        const float evf_[4] = {EV.x, EV.y, EV.z, EV.w};                      \
        const float vvf_[4] = {VV.x, VV.y, VV.z, VV.w};                      \
        _Pragma("unroll")                                                    \
        for (int l = 0; l < 4; ++l) {                                        \
            float x_ = qk_ + eaf_[l];                                        \
            x_ = fminf(fmaxf(x_, -5.f), 5.f);                                \
            const float e_ = __expf(x_);                                     \
            acc_d[l] = fmaf(e_, m_, acc_d[l]);                               \
            const float s2_ = e_ * m2_;                                      \
            acc_v[l] = fmaf(s2_, vvf_[l], acc_v[l]);                         \
            acc_e[l] = fmaf(s2_, evf_[l], acc_e[l]);                         \
        }                                                                    \
    } while (0)

    vf4 eaA, evA, vvA, eaB, evB, vvB;
    LOADSET(eaA, evA, vvA, 0);
    LOADSET(eaB, evB, vvB, 16);

    #pragma unroll
    for (int k = 0; k < 7; ++k) {
        const int jb = k * 32;
        COMPUTE(eaA, evA, vvA, jb);
        LOADSET(eaA, evA, vvA, jb + 32);
        COMPUTE(eaB, evB, vvB, jb + 16);
        LOADSET(eaB, evB, vvB, jb + 48);
    }
    COMPUTE(eaA, evA, vvA, 224);
    COMPUTE(eaB, evB, vvB, 240);

#undef LOADSET
#undef COMPUTE

    __syncthreads();

    // ---- reduce 16 j-partials per hk ----
    #pragma unroll
    for (int l = 0; l < 4; ++l) {
        red[0 * 2048 + joff * HK + hk4 + l] = acc_d[l];
        red[1 * 2048 + joff * HK + hk4 + l] = acc_v[l];
        red[2 * 2048 + joff * HK + hk4 + l] = acc_e[l];
    }
    __syncthreads();

    if (t < HK) {
        float D = 0.f, OV = 0.f, OE = 0.f;
        #pragma unroll
        for (int p = 0; p < 16; ++p) {
            D  += red[0 * 2048 + p * HK + t];
            OV += red[1 * 2048 + p * HK + t];
            OE += red[2 * 2048 + p * HK + t];
        }
        out[(size_t)bi * HK + t] = (OV + OE) / fmaxf(D, 1e-6f);
    }
}

extern "C" void kernel_launch(void* const* d_in, const int* in_sizes, int n_in,
                              void* d_out, int out_size, void* d_ws, size_t ws_size,
                              hipStream_t stream) {
    const float* h     = (const float*)d_in[0];
    const float* e_att = (const float*)d_in[1];
    const float* e_val = (const float*)d_in[2];
    const float* mask  = (const float*)d_in[3];
    const float* Wq    = (const float*)d_in[4];
    const float* Wk    = (const float*)d_in[5];
    const float* Wv    = (const float*)d_in[6];
    float* out = (float*)d_out;

    float* Qw  = (float*)d_ws;              // 131072 f32
    float* Kw  = Qw + (size_t)BN * HK;      // 131072 f32
    float* Vw  = Kw + (size_t)BN * HK;      // 131072 f32 (total 1.5 MiB)

    qkv_kernel<<<512, 128, 0, stream>>>(h, Wq, Wk, Wv, Qw, Kw, Vw);
    attn_kernel<<<BN, 512, 0, stream>>>(e_att, e_val, mask, Qw, Kw, Vw, out);
}